// Round 6
// baseline (123.387 us; speedup 1.0000x reference)
//
#include <hip/hip_runtime.h>
#include <hip/hip_bf16.h>
#include <math.h>

#define N      8192
#define FIN    94
#define FOUT   16
#define ALPHA  0.2f
#define BM     64            // rows per block (main kernel)
#define JCH    1024          // j-columns per block chunk
#define NCH    (N / JCH)     // 8 chunks
#define NRB    (N / BM)      // 128 row-blocks
#define NT_T   (JCH / 32)    // 32 col-tiles per chunk

// ws layout: bf16 Wh_t[16][8192] at byte 0 (256 KB), then f32 arrays.
#define AR_OFF 65536               // exp(s_src)
#define CR_OFF (AR_OFF + N)        // exp(0.2*s_src)
#define BX_OFF (AR_OFF + 2*N)      // exp(s_dst)
#define DX_OFF (AR_OFF + 3*N)      // exp(0.2*s_dst)
#define PN_OFF (AR_OFF + 4*N)            // partial numerators [NCH][N][FOUT]
#define PL_OFF (PN_OFF + NCH*N*FOUT)     // partial denominators [NCH][N]
// dead-write region for the A/B measurement copy
#define PN2_OFF (PL_OFF + NCH*N)
#define PL2_OFF (PN2_OFF + NCH*N*FOUT)

typedef int   i32x4 __attribute__((ext_vector_type(4)));
typedef float f32x4 __attribute__((ext_vector_type(4)));
typedef short s16x8 __attribute__((ext_vector_type(8)));

// Kernel 1: Wh (bf16, transposed) + four exp tables.
__global__ __launch_bounds__(256) void wh_score_kernel(
    const float* __restrict__ h, const float* __restrict__ W,
    const float* __restrict__ attn, float* __restrict__ ws)
{
    const int gid = blockIdx.x * 256 + threadIdx.x;  // 0..131071
    const int i = gid >> 4;
    const int k = gid & 15;
    const float* hrow = h + i * FIN;
    float a0 = 0.f, a1 = 0.f, a2 = 0.f, a3 = 0.f;
    #pragma unroll
    for (int c = 0; c < 92; c += 4) {
        a0 = fmaf(hrow[c],     W[c * FOUT + k],       a0);
        a1 = fmaf(hrow[c + 1], W[(c + 1) * FOUT + k], a1);
        a2 = fmaf(hrow[c + 2], W[(c + 2) * FOUT + k], a2);
        a3 = fmaf(hrow[c + 3], W[(c + 3) * FOUT + k], a3);
    }
    a0 = fmaf(hrow[92], W[92 * FOUT + k], a0);
    a1 = fmaf(hrow[93], W[93 * FOUT + k], a1);
    const float acc = (a0 + a1) + (a2 + a3);

    __hip_bfloat16* whtb = (__hip_bfloat16*)ws;
    whtb[k * N + i] = __float2bfloat16(acc);   // transposed bf16 store

    float ps = acc * attn[k];
    float pd = acc * attn[FOUT + k];
    #pragma unroll
    for (int mk = 1; mk < 16; mk <<= 1) {
        ps += __shfl_xor(ps, mk);
        pd += __shfl_xor(pd, mk);
    }
    if (k == 0) {
        ws[AR_OFF + i] = __expf(ps);
        ws[CR_OFF + i] = __expf(ALPHA * ps);
        ws[BX_OFF + i] = __expf(pd);
        ws[DX_OFF + i] = __expf(ALPHA * pd);
    }
}

template<bool NT>
__device__ __forceinline__ i32x4 ld16(const i32x4* p) {
    if constexpr (NT) return __builtin_nontemporal_load(p);
    else              return *p;
}

// Kernel 2 (main): MFMA masked-softmax-weighted accumulation, depth-4
// register-ring prefetch.  exp(leaky_relu(x)) == max(exp(x), exp(0.2x)).
// Templated on adj-load flavor for the A/B measurement copy.
template<bool NT>
__global__ __launch_bounds__(256, 4) void gat_mfma_kernel(
    const int* __restrict__ adj, const float* __restrict__ ws,
    float* __restrict__ wso, int pn_off, int pl_off)
{
    __shared__ float Bl[JCH];
    __shared__ float Dl[JCH];

    const int tid = threadIdx.x;
    const int rb = blockIdx.x & (NRB - 1);
    const int ch = blockIdx.x >> 7;          // NRB = 128
    const int i0 = rb * BM;
    const int jc0 = ch * JCH;

    {
        const int t4 = tid * 4;
        *(f32x4*)(Bl + t4) = *(const f32x4*)(ws + BX_OFF + jc0 + t4);
        *(f32x4*)(Dl + t4) = *(const f32x4*)(ws + DX_OFF + jc0 + t4);
    }
    __syncthreads();

    const int w    = tid >> 6;
    const int lane = tid & 63;
    const int c15  = lane & 15;   // A-row (local), B-col, C-col
    const int g    = lane >> 4;   // k-group: this lane covers k = 8g..8g+7
    const int arow = i0 + w * 16 + c15;

    const float Ar = ws[AR_OFF + arow];
    const float Cr = ws[CR_OFF + arow];

    const unsigned short* __restrict__ whtb = (const unsigned short*)ws;
    const int* __restrict__ ap            = adj + (size_t)arow * N + jc0 + 8 * g;
    const unsigned short* __restrict__ wp = whtb + c15 * N + jc0 + 8 * g;

    f32x4 acc = {0.f, 0.f, 0.f, 0.f};
    float lsum = 0.f;

    i32x4 a0_0, a1_0, a0_1, a1_1, a0_2, a1_2, a0_3, a1_3;
    s16x8 fb_0, fb_1, fb_2, fb_3;

#define ISSUE(s, t) do {                                                       \
    const int off_ = 32 * (t);                                                 \
    a0_##s = ld16<NT>((const i32x4*)(ap + off_));                              \
    a1_##s = ld16<NT>((const i32x4*)(ap + off_ + 4));                          \
    fb_##s = *(const s16x8*)(wp + off_);                                       \
} while (0)

#define COMPUTE(s, t) do {                                                     \
    const int lb = (t) * 32 + 8 * g;                                           \
    const f32x4 B0 = *(const f32x4*)(Bl + lb);                                 \
    const f32x4 B1 = *(const f32x4*)(Bl + lb + 4);                             \
    const f32x4 D0 = *(const f32x4*)(Dl + lb);                                 \
    const f32x4 D1 = *(const f32x4*)(Dl + lb + 4);                             \
    float wf[8];                                                               \
    _Pragma("unroll") for (int e = 0; e < 4; ++e) {                            \
        const float ww = (a0_##s[e] > 0) ?                                     \
            fmaxf(Ar * B0[e], Cr * D0[e]) : 0.0f;                              \
        wf[e] = ww; lsum += ww;                                                \
    }                                                                          \
    _Pragma("unroll") for (int e = 0; e < 4; ++e) {                            \
        const float ww = (a1_##s[e] > 0) ?                                     \
            fmaxf(Ar * B1[e], Cr * D1[e]) : 0.0f;                              \
        wf[4 + e] = ww; lsum += ww;                                            \
    }                                                                          \
    s16x8 fa;                                                                  \
    _Pragma("unroll") for (int e = 0; e < 8; ++e)                              \
        fa[e] = (short)__builtin_bit_cast(unsigned short,                      \
                                          __float2bfloat16(wf[e]));           \
    acc = __builtin_amdgcn_mfma_f32_16x16x32_bf16(fa, fb_##s, acc, 0, 0, 0);   \
} while (0)

    ISSUE(0, 0); ISSUE(1, 1); ISSUE(2, 2); ISSUE(3, 3);

    #pragma unroll 1
    for (int t = 0; t < NT_T - 4; t += 4) {
        COMPUTE(0, t);     ISSUE(0, t + 4);
        COMPUTE(1, t + 1); ISSUE(1, t + 5);
        COMPUTE(2, t + 2); ISSUE(2, t + 6);
        COMPUTE(3, t + 3); ISSUE(3, t + 7);
    }
    COMPUTE(0, NT_T - 4); COMPUTE(1, NT_T - 3);
    COMPUTE(2, NT_T - 2); COMPUTE(3, NT_T - 1);
#undef ISSUE
#undef COMPUTE

    lsum += __shfl_xor(lsum, 16);
    lsum += __shfl_xor(lsum, 32);

    // C/D layout (m89-verified): col = lane&15, row = (lane>>4)*4 + reg
    #pragma unroll
    for (int r = 0; r < 4; ++r) {
        const int grow = i0 + w * 16 + 4 * g + r;
        wso[pn_off + ((size_t)ch * N + grow) * FOUT + c15] = acc[r];
    }
    if (g == 0)
        wso[pl_off + ch * N + arow] = lsum;
}

// Kernel 3: sum partials over chunks, normalize, ELU.
__global__ __launch_bounds__(256) void reduce_kernel(
    const float* __restrict__ ws, float* __restrict__ out)
{
    const int gid = blockIdx.x * 256 + threadIdx.x;   // 0..131071
    const int i = gid >> 4;
    float num = 0.f, den = 0.f;
    #pragma unroll
    for (int ch = 0; ch < NCH; ++ch) {
        num += ws[PN_OFF + (size_t)ch * (N * FOUT) + gid];
        den += ws[PL_OFF + ch * N + i];
    }
    const float v = num / den;
    out[gid] = (v > 0.0f) ? v : expm1f(v);   // ELU
}

extern "C" void kernel_launch(void* const* d_in, const int* in_sizes, int n_in,
                              void* d_out, int out_size, void* d_ws, size_t ws_size,
                              hipStream_t stream)
{
    const float* h    = (const float*)d_in[0];
    const int*   adj  = (const int*)d_in[1];
    const float* W    = (const float*)d_in[2];
    const float* attn = (const float*)d_in[3];
    float* out = (float*)d_out;
    float* ws  = (float*)d_ws;

    wh_score_kernel<<<(N * FOUT) / 256, 256, 0, stream>>>(h, W, attn, ws);
    // real pass (nt loads, as in round 5) -> real partials
    gat_mfma_kernel<true><<<NRB * NCH, 256, 0, stream>>>(adj, ws, ws,
                                                         PN_OFF, PL_OFF);
    // measurement copy (plain cached loads) -> dead partials; idempotent,
    // deterministic; Delta(total) vs round 5 == its exact duration.
    gat_mfma_kernel<false><<<NRB * NCH, 256, 0, stream>>>(adj, ws, ws,
                                                          PN2_OFF, PL2_OFF);
    reduce_kernel<<<(N * FOUT) / 256, 256, 0, stream>>>(ws, out);
}

// Round 7
// 58.979 us; speedup vs baseline: 2.0921x; 2.0921x over previous
//
#include <hip/hip_runtime.h>
#include <hip/hip_bf16.h>
#include <math.h>

#define N      8192
#define FIN    94
#define FOUT   16
#define ALPHA  0.2f
#define BM     64            // rows per block (main kernel)
#define JCH    1024          // j-columns per block chunk
#define NCH    (N / JCH)     // 8 chunks
#define NRB    (N / BM)      // 128 row-blocks
#define NT_T   (JCH / 32)    // 32 col-tiles per chunk

// ws layout: bf16 Wh_t[16][8192] at byte 0 (256 KB), then f32 arrays.
#define AR_OFF 65536               // exp(s_src)
#define CR_OFF (AR_OFF + N)        // exp(0.2*s_src)
#define BX_OFF (AR_OFF + 2*N)      // exp(s_dst)
#define DX_OFF (AR_OFF + 3*N)      // exp(0.2*s_dst)
#define PN_OFF (AR_OFF + 4*N)            // partial numerators [NCH][N][FOUT]
#define PL_OFF (PN_OFF + NCH*N*FOUT)     // partial denominators [NCH][N]

typedef int   i32x4 __attribute__((ext_vector_type(4)));
typedef float f32x4 __attribute__((ext_vector_type(4)));
typedef short s16x8 __attribute__((ext_vector_type(8)));

// Kernel 1: Wh (bf16, transposed) + four exp tables.
__global__ __launch_bounds__(256) void wh_score_kernel(
    const float* __restrict__ h, const float* __restrict__ W,
    const float* __restrict__ attn, float* __restrict__ ws)
{
    const int gid = blockIdx.x * 256 + threadIdx.x;  // 0..131071
    const int i = gid >> 4;
    const int k = gid & 15;
    const float* hrow = h + i * FIN;
    float a0 = 0.f, a1 = 0.f, a2 = 0.f, a3 = 0.f;
    #pragma unroll
    for (int c = 0; c < 92; c += 4) {
        a0 = fmaf(hrow[c],     W[c * FOUT + k],       a0);
        a1 = fmaf(hrow[c + 1], W[(c + 1) * FOUT + k], a1);
        a2 = fmaf(hrow[c + 2], W[(c + 2) * FOUT + k], a2);
        a3 = fmaf(hrow[c + 3], W[(c + 3) * FOUT + k], a3);
    }
    a0 = fmaf(hrow[92], W[92 * FOUT + k], a0);
    a1 = fmaf(hrow[93], W[93 * FOUT + k], a1);
    const float acc = (a0 + a1) + (a2 + a3);

    __hip_bfloat16* whtb = (__hip_bfloat16*)ws;
    whtb[k * N + i] = __float2bfloat16(acc);   // transposed bf16 store

    float ps = acc * attn[k];
    float pd = acc * attn[FOUT + k];
    #pragma unroll
    for (int mk = 1; mk < 16; mk <<= 1) {
        ps += __shfl_xor(ps, mk);
        pd += __shfl_xor(pd, mk);
    }
    if (k == 0) {
        // |scores| small: exp() safe in f32, softmax shift-invariant -> no max pass.
        ws[AR_OFF + i] = __expf(ps);
        ws[CR_OFF + i] = __expf(ALPHA * ps);
        ws[BX_OFF + i] = __expf(pd);
        ws[DX_OFF + i] = __expf(ALPHA * pd);
    }
}

// Kernel 2 (main): MFMA masked-softmax-weighted accumulation, depth-4
// register-ring prefetch, PLAIN cached adj loads (round-6 A/B: nt loads run
// ~74us, plain run ~42us = HBM roofline for the 256 MB adj stream).
__global__ __launch_bounds__(256, 4) void gat_mfma_kernel(
    const int* __restrict__ adj, const float* __restrict__ ws,
    float* __restrict__ wso)
{
    __shared__ float Bl[JCH];
    __shared__ float Dl[JCH];

    const int tid = threadIdx.x;
    const int rb = blockIdx.x & (NRB - 1);
    const int ch = blockIdx.x >> 7;          // NRB = 128
    const int i0 = rb * BM;
    const int jc0 = ch * JCH;

    // stage B/D tables for this chunk into LDS
    {
        const int t4 = tid * 4;
        *(f32x4*)(Bl + t4) = *(const f32x4*)(ws + BX_OFF + jc0 + t4);
        *(f32x4*)(Dl + t4) = *(const f32x4*)(ws + DX_OFF + jc0 + t4);
    }
    __syncthreads();

    const int w    = tid >> 6;
    const int lane = tid & 63;
    const int c15  = lane & 15;   // A-row (local), B-col, C-col
    const int g    = lane >> 4;   // k-group: this lane covers k = 8g..8g+7
    const int arow = i0 + w * 16 + c15;

    const float Ar = ws[AR_OFF + arow];
    const float Cr = ws[CR_OFF + arow];

    const unsigned short* __restrict__ whtb = (const unsigned short*)ws;
    const int* __restrict__ ap            = adj + (size_t)arow * N + jc0 + 8 * g;
    const unsigned short* __restrict__ wp = whtb + c15 * N + jc0 + 8 * g;

    f32x4 acc = {0.f, 0.f, 0.f, 0.f};
    float lsum = 0.f;

    i32x4 a0_0, a1_0, a0_1, a1_1, a0_2, a1_2, a0_3, a1_3;
    s16x8 fb_0, fb_1, fb_2, fb_3;

#define ISSUE(s, t) do {                                                       \
    const int off_ = 32 * (t);                                                 \
    a0_##s = *(const i32x4*)(ap + off_);                                       \
    a1_##s = *(const i32x4*)(ap + off_ + 4);                                   \
    fb_##s = *(const s16x8*)(wp + off_);                                       \
} while (0)

#define COMPUTE(s, t) do {                                                     \
    const int lb = (t) * 32 + 8 * g;                                           \
    const f32x4 B0 = *(const f32x4*)(Bl + lb);                                 \
    const f32x4 B1 = *(const f32x4*)(Bl + lb + 4);                             \
    const f32x4 D0 = *(const f32x4*)(Dl + lb);                                 \
    const f32x4 D1 = *(const f32x4*)(Dl + lb + 4);                             \
    float wf[8];                                                               \
    _Pragma("unroll") for (int e = 0; e < 4; ++e) {                            \
        const float ww = (a0_##s[e] > 0) ?                                     \
            fmaxf(Ar * B0[e], Cr * D0[e]) : 0.0f;                              \
        wf[e] = ww; lsum += ww;                                                \
    }                                                                          \
    _Pragma("unroll") for (int e = 0; e < 4; ++e) {                            \
        const float ww = (a1_##s[e] > 0) ?                                     \
            fmaxf(Ar * B1[e], Cr * D1[e]) : 0.0f;                              \
        wf[4 + e] = ww; lsum += ww;                                            \
    }                                                                          \
    s16x8 fa;                                                                  \
    _Pragma("unroll") for (int e = 0; e < 8; ++e)                              \
        fa[e] = (short)__builtin_bit_cast(unsigned short,                      \
                                          __float2bfloat16(wf[e]));           \
    acc = __builtin_amdgcn_mfma_f32_16x16x32_bf16(fa, fb_##s, acc, 0, 0, 0);   \
} while (0)

    ISSUE(0, 0); ISSUE(1, 1); ISSUE(2, 2); ISSUE(3, 3);

    #pragma unroll 1
    for (int t = 0; t < NT_T - 4; t += 4) {
        COMPUTE(0, t);     ISSUE(0, t + 4);
        COMPUTE(1, t + 1); ISSUE(1, t + 5);
        COMPUTE(2, t + 2); ISSUE(2, t + 6);
        COMPUTE(3, t + 3); ISSUE(3, t + 7);
    }
    COMPUTE(0, NT_T - 4); COMPUTE(1, NT_T - 3);
    COMPUTE(2, NT_T - 2); COMPUTE(3, NT_T - 1);
#undef ISSUE
#undef COMPUTE

    // denominator: reduce lane partials across the 4 k-groups
    lsum += __shfl_xor(lsum, 16);
    lsum += __shfl_xor(lsum, 32);

    // C/D layout (m89-verified): col = lane&15, row = (lane>>4)*4 + reg
    #pragma unroll
    for (int r = 0; r < 4; ++r) {
        const int grow = i0 + w * 16 + 4 * g + r;
        wso[PN_OFF + ((size_t)ch * N + grow) * FOUT + c15] = acc[r];
    }
    if (g == 0)
        wso[PL_OFF + ch * N + arow] = lsum;
}

// Kernel 3: sum partials over chunks, normalize, ELU.
__global__ __launch_bounds__(256) void reduce_kernel(
    const float* __restrict__ ws, float* __restrict__ out)
{
    const int gid = blockIdx.x * 256 + threadIdx.x;   // 0..131071
    const int i = gid >> 4;
    float num = 0.f, den = 0.f;
    #pragma unroll
    for (int ch = 0; ch < NCH; ++ch) {
        num += ws[PN_OFF + (size_t)ch * (N * FOUT) + gid];
        den += ws[PL_OFF + ch * N + i];
    }
    const float v = num / den;
    out[gid] = (v > 0.0f) ? v : expm1f(v);   // ELU
}

extern "C" void kernel_launch(void* const* d_in, const int* in_sizes, int n_in,
                              void* d_out, int out_size, void* d_ws, size_t ws_size,
                              hipStream_t stream)
{
    const float* h    = (const float*)d_in[0];
    const int*   adj  = (const int*)d_in[1];
    const float* W    = (const float*)d_in[2];
    const float* attn = (const float*)d_in[3];
    float* out = (float*)d_out;
    float* ws  = (float*)d_ws;

    wh_score_kernel<<<(N * FOUT) / 256, 256, 0, stream>>>(h, W, attn, ws);
    gat_mfma_kernel<<<NRB * NCH, 256, 0, stream>>>(adj, ws, ws);
    reduce_kernel<<<(N * FOUT) / 256, 256, 0, stream>>>(ws, out);
}